// Round 1
// baseline (800.660 us; speedup 1.0000x reference)
//
#include <hip/hip_runtime.h>
#include <math.h>

#define N_NODES 100000
#define HID 128

// ---------------------------------------------------------------------------
// Embedding/concat: h0 = [x(64) | user_emb(32) | loc_emb(16) | time@Wt+bt(16)]
// ---------------------------------------------------------------------------
__global__ __launch_bounds__(256) void k_embed(
    const float* __restrict__ x, const int* __restrict__ uid,
    const int* __restrict__ lid, const float* __restrict__ timef,
    const float* __restrict__ utab, const float* __restrict__ ltab,
    const float* __restrict__ Wt, const float* __restrict__ bt,
    float* __restrict__ h0) {
  int t = threadIdx.x;
  int v = blockIdx.x * 2 + (t >> 7);
  int f = t & 127;
  if (v >= N_NODES) return;
  float val;
  if (f < 64) {
    val = x[v * 64 + f];
  } else if (f < 96) {
    val = utab[uid[v] * 32 + (f - 64)];
  } else if (f < 112) {
    val = ltab[lid[v] * 16 + (f - 96)];
  } else {
    int c = f - 112;
    float acc = bt[c];
#pragma unroll
    for (int j = 0; j < 4; ++j) acc += timef[v * 4 + j] * Wt[j * 16 + c];
    val = acc;
  }
  h0[v * 128 + f] = val;
}

// ---------------------------------------------------------------------------
// CSR build: degree count -> scan -> fill
// ---------------------------------------------------------------------------
__global__ void k_deg(const int* __restrict__ dst, int* __restrict__ deg, int E) {
  int e = blockIdx.x * 256 + threadIdx.x;
  if (e >= E) return;
  atomicAdd(&deg[dst[e]], 1);
}

__global__ void k_scan_a(const int* __restrict__ deg, int* __restrict__ partial) {
  __shared__ int s[1024];
  int t = threadIdx.x;
  int i = blockIdx.x * 1024 + t;
  s[t] = (i < N_NODES) ? deg[i] : 0;
  __syncthreads();
  for (int off = 512; off > 0; off >>= 1) {
    if (t < off) s[t] += s[t + off];
    __syncthreads();
  }
  if (t == 0) partial[blockIdx.x] = s[0];
}

__global__ void k_scan_b(const int* __restrict__ partial, int* __restrict__ poff,
                         int* __restrict__ row_ptr, int nb) {
  if (threadIdx.x == 0 && blockIdx.x == 0) {
    int run = 0;
    for (int b = 0; b < nb; ++b) {
      poff[b] = run;
      run += partial[b];
    }
    row_ptr[N_NODES] = run;
  }
}

__global__ void k_scan_c(const int* __restrict__ deg, const int* __restrict__ poff,
                         int* __restrict__ row_ptr, int* __restrict__ cursor) {
  __shared__ int s[1024];
  int t = threadIdx.x;
  int i = blockIdx.x * 1024 + t;
  int d = (i < N_NODES) ? deg[i] : 0;
  s[t] = d;
  __syncthreads();
  for (int off = 1; off < 1024; off <<= 1) {
    int add = (t >= off) ? s[t - off] : 0;
    __syncthreads();
    s[t] += add;
    __syncthreads();
  }
  if (i < N_NODES) {
    int ex = poff[blockIdx.x] + s[t] - d;  // exclusive prefix
    row_ptr[i] = ex;
    cursor[i] = ex;
  }
}

__global__ void k_fill(const int* __restrict__ src, const int* __restrict__ dst,
                       int* __restrict__ cursor, int* __restrict__ col, int E) {
  int e = blockIdx.x * 256 + threadIdx.x;
  if (e >= E) return;
  int d = dst[e];
  int pos = atomicAdd(&cursor[d], 1);
  col[pos] = src[e];
}

// ---------------------------------------------------------------------------
// Mean aggregation: agg[v] = (1/max(deg,1)) * sum_{u in in(v)} h[u]
// one node per 128-thread block; thread = feature. Coalesced 512B row reads.
// ---------------------------------------------------------------------------
__global__ __launch_bounds__(128) void k_agg(
    const float* __restrict__ h, const int* __restrict__ rp,
    const int* __restrict__ col, float* __restrict__ agg) {
  int v = blockIdx.x;
  int f = threadIdx.x;
  int s0 = rp[v], s1 = rp[v + 1];
  float acc = 0.f;
  int j = s0;
  for (; j + 4 <= s1; j += 4) {
    int c0 = col[j], c1 = col[j + 1], c2 = col[j + 2], c3 = col[j + 3];
    acc += h[c0 * 128 + f];
    acc += h[c1 * 128 + f];
    acc += h[c2 * 128 + f];
    acc += h[c3 * 128 + f];
  }
  for (; j < s1; ++j) acc += h[col[j] * 128 + f];
  int deg = s1 - s0;
  agg[v * 128 + f] = acc / (float)(deg > 0 ? deg : 1);
}

// ---------------------------------------------------------------------------
// Fused dual GEMM + bias + ReLU:
//   hout[v] = relu(agg[v] @ Wl + hin[v] @ Wr + b)
// Tiling: 64 nodes/block, 256 threads, BK=32, 8 k-chunks (4 on agg/Wl, 4 on
// hin/Wr). A staged transposed in LDS, W staged contiguous. Each thread owns
// a 4-node x 8-feature accumulator tile.
// ---------------------------------------------------------------------------
__global__ __launch_bounds__(256) void k_gemm(
    const float* __restrict__ agg, const float* __restrict__ hin,
    const float* __restrict__ Wl, const float* __restrict__ Wr,
    const float* __restrict__ bias, float* __restrict__ hout) {
  __shared__ float As[32 * 64];    // [k][node]
  __shared__ float Ws[32 * 128];   // [k][f]
  int t = threadIdx.x;
  int fg = t & 15;   // feature group: f = fg*8 .. fg*8+7
  int ng = t >> 4;   // node group:    n = ng*4 .. ng*4+3
  int mbase = blockIdx.x * 64;

  float acc[4][8];
#pragma unroll
  for (int i = 0; i < 4; ++i)
#pragma unroll
    for (int j = 0; j < 8; ++j) acc[i][j] = 0.f;

  for (int c = 0; c < 8; ++c) {
    const float* Ap = (c < 4) ? agg : hin;
    const float* Wp = (c < 4) ? Wl : Wr;
    int ko = (c & 3) * 32;
    __syncthreads();
    // stage A chunk transposed: As[k][node]
    for (int i = t; i < 512; i += 256) {
      int node = i >> 3;
      int q = i & 7;
      int gn = mbase + node;
      float4 val = make_float4(0.f, 0.f, 0.f, 0.f);
      if (gn < N_NODES) val = *(const float4*)&Ap[gn * 128 + ko + q * 4];
      As[(q * 4 + 0) * 64 + node] = val.x;
      As[(q * 4 + 1) * 64 + node] = val.y;
      As[(q * 4 + 2) * 64 + node] = val.z;
      As[(q * 4 + 3) * 64 + node] = val.w;
    }
    // stage W chunk: rows ko..ko+31, contiguous 16KB
    for (int i = t; i < 1024; i += 256) {
      *(float4*)&Ws[i * 4] = *(const float4*)&Wp[ko * 128 + i * 4];
    }
    __syncthreads();
#pragma unroll 8
    for (int kk = 0; kk < 32; ++kk) {
      const float4 av = *(const float4*)&As[kk * 64 + ng * 4];
      const float4 w0 = *(const float4*)&Ws[kk * 128 + fg * 8];
      const float4 w1 = *(const float4*)&Ws[kk * 128 + fg * 8 + 4];
      const float a_[4] = {av.x, av.y, av.z, av.w};
      const float w_[8] = {w0.x, w0.y, w0.z, w0.w, w1.x, w1.y, w1.z, w1.w};
#pragma unroll
      for (int i = 0; i < 4; ++i)
#pragma unroll
        for (int j = 0; j < 8; ++j) acc[i][j] += a_[i] * w_[j];
    }
  }

  float bv[8];
#pragma unroll
  for (int j = 0; j < 8; ++j) bv[j] = bias[fg * 8 + j];
#pragma unroll
  for (int i = 0; i < 4; ++i) {
    int node = mbase + ng * 4 + i;
    if (node < N_NODES) {
      float4 o0, o1;
      o0.x = fmaxf(acc[i][0] + bv[0], 0.f);
      o0.y = fmaxf(acc[i][1] + bv[1], 0.f);
      o0.z = fmaxf(acc[i][2] + bv[2], 0.f);
      o0.w = fmaxf(acc[i][3] + bv[3], 0.f);
      o1.x = fmaxf(acc[i][4] + bv[4], 0.f);
      o1.y = fmaxf(acc[i][5] + bv[5], 0.f);
      o1.z = fmaxf(acc[i][6] + bv[6], 0.f);
      o1.w = fmaxf(acc[i][7] + bv[7], 0.f);
      *(float4*)&hout[node * 128 + fg * 8] = o0;
      *(float4*)&hout[node * 128 + fg * 8 + 4] = o1;
    }
  }
}

// ---------------------------------------------------------------------------
// Classifier: out[v] = sigmoid(h[v] . Wc + bc). One wave per node.
// ---------------------------------------------------------------------------
__global__ __launch_bounds__(256) void k_cls(
    const float* __restrict__ h, const float* __restrict__ Wc,
    const float* __restrict__ bc, float* __restrict__ out) {
  int t = threadIdx.x;
  int lane = t & 63;
  int v = blockIdx.x * 4 + (t >> 6);
  if (v >= N_NODES) return;
  float p = h[v * 128 + lane] * Wc[lane] + h[v * 128 + 64 + lane] * Wc[64 + lane];
#pragma unroll
  for (int off = 32; off > 0; off >>= 1) p += __shfl_down(p, off);
  if (lane == 0) out[v] = 1.f / (1.f + expf(-(p + bc[0])));
}

// ---------------------------------------------------------------------------
extern "C" void kernel_launch(void* const* d_in, const int* in_sizes, int n_in,
                              void* d_out, int out_size, void* d_ws, size_t ws_size,
                              hipStream_t stream) {
  const float* x     = (const float*)d_in[0];
  const int*   eidx  = (const int*)d_in[1];
  const int*   uid   = (const int*)d_in[2];
  const int*   lid   = (const int*)d_in[3];
  const float* timef = (const float*)d_in[4];
  const float* utab  = (const float*)d_in[5];
  const float* ltab  = (const float*)d_in[6];
  const float* Wt    = (const float*)d_in[7];
  const float* bt    = (const float*)d_in[8];
  const float* W1l   = (const float*)d_in[9];
  const float* b1    = (const float*)d_in[10];
  const float* W1r   = (const float*)d_in[11];
  const float* W2l   = (const float*)d_in[12];
  const float* b2    = (const float*)d_in[13];
  const float* W2r   = (const float*)d_in[14];
  const float* Wc    = (const float*)d_in[15];
  const float* bc    = (const float*)d_in[16];
  float* out = (float*)d_out;

  const int E = in_sizes[1] / 2;
  const int* src = eidx;
  const int* dst = eidx + E;

  char* ws = (char*)d_ws;
  size_t off = 0;
  auto alloc = [&](size_t bytes) -> void* {
    void* p = ws + off;
    off += (bytes + 255) & ~(size_t)255;
    return p;
  };
  const size_t HBYTES = (size_t)N_NODES * 128 * sizeof(float);
  float* h0      = (float*)alloc(HBYTES);           // h0, later h2
  float* h1      = (float*)alloc(HBYTES);
  float* agg     = (float*)alloc(HBYTES);
  int*   deg     = (int*)alloc((size_t)N_NODES * 4);
  int*   row_ptr = (int*)alloc((size_t)(N_NODES + 1) * 4);
  int*   cursor  = (int*)alloc((size_t)N_NODES * 4);
  int*   col     = (int*)alloc((size_t)E * 4);
  int*   partial = (int*)alloc(1024);
  int*   poff    = (int*)alloc(1024);
  (void)ws_size; (void)n_in; (void)out_size;

  // ---- embed + CSR build ----
  hipMemsetAsync(deg, 0, (size_t)N_NODES * 4, stream);
  k_embed<<<(N_NODES + 1) / 2, 256, 0, stream>>>(x, uid, lid, timef, utab, ltab, Wt, bt, h0);
  k_deg<<<(E + 255) / 256, 256, 0, stream>>>(dst, deg, E);
  int nb = (N_NODES + 1023) / 1024;
  k_scan_a<<<nb, 1024, 0, stream>>>(deg, partial);
  k_scan_b<<<1, 64, 0, stream>>>(partial, poff, row_ptr, nb);
  k_scan_c<<<nb, 1024, 0, stream>>>(deg, poff, row_ptr, cursor);
  k_fill<<<(E + 255) / 256, 256, 0, stream>>>(src, dst, cursor, col, E);

  // ---- layer 1 ----
  k_agg<<<N_NODES, 128, 0, stream>>>(h0, row_ptr, col, agg);
  k_gemm<<<(N_NODES + 63) / 64, 256, 0, stream>>>(agg, h0, W1l, W1r, b1, h1);

  // ---- layer 2 (h2 reuses h0 buffer) ----
  k_agg<<<N_NODES, 128, 0, stream>>>(h1, row_ptr, col, agg);
  k_gemm<<<(N_NODES + 63) / 64, 256, 0, stream>>>(agg, h1, W2l, W2r, b2, h0);

  // ---- classifier ----
  k_cls<<<(N_NODES + 3) / 4, 256, 0, stream>>>(h0, Wc, bc, out);
}

// Round 2
// 709.298 us; speedup vs baseline: 1.1288x; 1.1288x over previous
//
#include <hip/hip_runtime.h>
#include <math.h>

#define N_NODES 100000
#define HID 128
#define NB 782          // ceil(N_NODES / 128) buckets, 128 dst nodes each
#define CAP 4096        // per-bucket edge capacity (mean 2046, sigma ~45)

// ---------------------------------------------------------------------------
// Embedding/concat: h0 = [x(64) | user_emb(32) | loc_emb(16) | time@Wt+bt(16)]
// ---------------------------------------------------------------------------
__global__ __launch_bounds__(256) void k_embed(
    const float* __restrict__ x, const int* __restrict__ uid,
    const int* __restrict__ lid, const float* __restrict__ timef,
    const float* __restrict__ utab, const float* __restrict__ ltab,
    const float* __restrict__ Wt, const float* __restrict__ bt,
    float* __restrict__ h0) {
  int t = threadIdx.x;
  int v = blockIdx.x * 2 + (t >> 7);
  int f = t & 127;
  if (v >= N_NODES) return;
  float val;
  if (f < 64) {
    val = x[v * 64 + f];
  } else if (f < 96) {
    val = utab[uid[v] * 32 + (f - 64)];
  } else if (f < 112) {
    val = ltab[lid[v] * 16 + (f - 96)];
  } else {
    int c = f - 112;
    float acc = bt[c];
#pragma unroll
    for (int j = 0; j < 4; ++j) acc += timef[v * 4 + j] * Wt[j * 16 + c];
    val = acc;
  }
  h0[v * 128 + f] = val;
}

// ---------------------------------------------------------------------------
// Bucketed CSR build.
// Pass A: scatter edges into 782 buckets by dst>>7. Counters padded to one
// cache line each (stride 16 ints) to spread atomic traffic across L2 lines.
// Packed entry: (src << 7) | (dst & 127)  — src < 2^17, fits 24 bits.
// ---------------------------------------------------------------------------
__global__ __launch_bounds__(256) void k_bucket(
    const int* __restrict__ src, const int* __restrict__ dst,
    int* __restrict__ bcnt, unsigned* __restrict__ bdata, int E) {
  int e = blockIdx.x * 256 + threadIdx.x;
  if (e >= E) return;
  int d = dst[e];
  int s = src[e];
  int b = d >> 7;
  int pos = atomicAdd(&bcnt[b * 16], 1);
  if (pos < CAP) bdata[(size_t)b * CAP + pos] = ((unsigned)s << 7) | (unsigned)(d & 127);
}

// Pass B: exclusive scan of bucket counts -> bucket base in col[]; total -> row_ptr[N]
__global__ __launch_bounds__(1024) void k_bscan(
    const int* __restrict__ bcnt, int* __restrict__ bbase,
    int* __restrict__ row_ptr) {
  __shared__ int s[1024];
  int t = threadIdx.x;
  int c = (t < NB) ? min(bcnt[t * 16], CAP) : 0;
  s[t] = c;
  __syncthreads();
  for (int off = 1; off < 1024; off <<= 1) {
    int add = (t >= off) ? s[t - off] : 0;
    __syncthreads();
    s[t] += add;
    __syncthreads();
  }
  if (t < NB) bbase[t] = s[t] - c;  // exclusive prefix
  if (t == NB - 1) row_ptr[N_NODES] = s[t];
}

// Pass C: per-bucket local counting sort. LDS atomics only; col writes land
// in the bucket's contiguous ~8KB CSR segment (L2-resident).
__global__ __launch_bounds__(256) void k_bfill(
    const int* __restrict__ bcnt, const int* __restrict__ bbase,
    const unsigned* __restrict__ bdata, int* __restrict__ row_ptr,
    int* __restrict__ col) {
  __shared__ unsigned sdata[3072];
  __shared__ int lcnt[128];
  __shared__ int loff[128];
  int b = blockIdx.x;
  int t = threadIdx.x;
  int cnt = min(bcnt[b * 16], CAP);
  int base = bbase[b];
  if (t < 128) lcnt[t] = 0;
  __syncthreads();
  const unsigned* bd = bdata + (size_t)b * CAP;
  for (int i = t; i < cnt; i += 256) {
    unsigned v = bd[i];
    if (i < 3072) sdata[i] = v;
    atomicAdd(&lcnt[v & 127u], 1);
  }
  __syncthreads();
  if (t < 128) loff[t] = lcnt[t];
  __syncthreads();
  for (int off = 1; off < 128; off <<= 1) {
    int add = 0;
    if (t < 128 && t >= off) add = loff[t - off];
    __syncthreads();
    if (t < 128) loff[t] += add;
    __syncthreads();
  }
  int node0 = b * 128;
  if (t < 128) {
    int excl = loff[t] - lcnt[t];
    if (node0 + t < N_NODES) row_ptr[node0 + t] = base + excl;
    lcnt[t] = excl;  // becomes the scatter cursor
  }
  __syncthreads();
  for (int i = t; i < cnt; i += 256) {
    unsigned v = (i < 3072) ? sdata[i] : bd[i];
    int pos = base + atomicAdd(&lcnt[v & 127u], 1);
    col[pos] = (int)(v >> 7);
  }
}

// ---------------------------------------------------------------------------
// Mean aggregation: agg[v] = (1/max(deg,1)) * sum_{u in in(v)} h[u]
// ---------------------------------------------------------------------------
__global__ __launch_bounds__(128) void k_agg(
    const float* __restrict__ h, const int* __restrict__ rp,
    const int* __restrict__ col, float* __restrict__ agg) {
  int v = blockIdx.x;
  int f = threadIdx.x;
  int s0 = rp[v], s1 = rp[v + 1];
  float acc = 0.f;
  int j = s0;
  for (; j + 4 <= s1; j += 4) {
    int c0 = col[j], c1 = col[j + 1], c2 = col[j + 2], c3 = col[j + 3];
    acc += h[c0 * 128 + f];
    acc += h[c1 * 128 + f];
    acc += h[c2 * 128 + f];
    acc += h[c3 * 128 + f];
  }
  for (; j < s1; ++j) acc += h[col[j] * 128 + f];
  int deg = s1 - s0;
  agg[v * 128 + f] = acc / (float)(deg > 0 ? deg : 1);
}

// ---------------------------------------------------------------------------
// Fused dual GEMM + bias + ReLU: hout[v] = relu(agg[v]@Wl + hin[v]@Wr + b)
// ---------------------------------------------------------------------------
__global__ __launch_bounds__(256) void k_gemm(
    const float* __restrict__ agg, const float* __restrict__ hin,
    const float* __restrict__ Wl, const float* __restrict__ Wr,
    const float* __restrict__ bias, float* __restrict__ hout) {
  __shared__ float As[32 * 64];    // [k][node]
  __shared__ float Ws[32 * 128];   // [k][f]
  int t = threadIdx.x;
  int fg = t & 15;
  int ng = t >> 4;
  int mbase = blockIdx.x * 64;

  float acc[4][8];
#pragma unroll
  for (int i = 0; i < 4; ++i)
#pragma unroll
    for (int j = 0; j < 8; ++j) acc[i][j] = 0.f;

  for (int c = 0; c < 8; ++c) {
    const float* Ap = (c < 4) ? agg : hin;
    const float* Wp = (c < 4) ? Wl : Wr;
    int ko = (c & 3) * 32;
    __syncthreads();
    for (int i = t; i < 512; i += 256) {
      int node = i >> 3;
      int q = i & 7;
      int gn = mbase + node;
      float4 val = make_float4(0.f, 0.f, 0.f, 0.f);
      if (gn < N_NODES) val = *(const float4*)&Ap[gn * 128 + ko + q * 4];
      As[(q * 4 + 0) * 64 + node] = val.x;
      As[(q * 4 + 1) * 64 + node] = val.y;
      As[(q * 4 + 2) * 64 + node] = val.z;
      As[(q * 4 + 3) * 64 + node] = val.w;
    }
    for (int i = t; i < 1024; i += 256) {
      *(float4*)&Ws[i * 4] = *(const float4*)&Wp[ko * 128 + i * 4];
    }
    __syncthreads();
#pragma unroll 8
    for (int kk = 0; kk < 32; ++kk) {
      const float4 av = *(const float4*)&As[kk * 64 + ng * 4];
      const float4 w0 = *(const float4*)&Ws[kk * 128 + fg * 8];
      const float4 w1 = *(const float4*)&Ws[kk * 128 + fg * 8 + 4];
      const float a_[4] = {av.x, av.y, av.z, av.w};
      const float w_[8] = {w0.x, w0.y, w0.z, w0.w, w1.x, w1.y, w1.z, w1.w};
#pragma unroll
      for (int i = 0; i < 4; ++i)
#pragma unroll
        for (int j = 0; j < 8; ++j) acc[i][j] += a_[i] * w_[j];
    }
  }

  float bv[8];
#pragma unroll
  for (int j = 0; j < 8; ++j) bv[j] = bias[fg * 8 + j];
#pragma unroll
  for (int i = 0; i < 4; ++i) {
    int node = mbase + ng * 4 + i;
    if (node < N_NODES) {
      float4 o0, o1;
      o0.x = fmaxf(acc[i][0] + bv[0], 0.f);
      o0.y = fmaxf(acc[i][1] + bv[1], 0.f);
      o0.z = fmaxf(acc[i][2] + bv[2], 0.f);
      o0.w = fmaxf(acc[i][3] + bv[3], 0.f);
      o1.x = fmaxf(acc[i][4] + bv[4], 0.f);
      o1.y = fmaxf(acc[i][5] + bv[5], 0.f);
      o1.z = fmaxf(acc[i][6] + bv[6], 0.f);
      o1.w = fmaxf(acc[i][7] + bv[7], 0.f);
      *(float4*)&hout[node * 128 + fg * 8] = o0;
      *(float4*)&hout[node * 128 + fg * 8 + 4] = o1;
    }
  }
}

// ---------------------------------------------------------------------------
// Classifier: out[v] = sigmoid(h[v] . Wc + bc)
// ---------------------------------------------------------------------------
__global__ __launch_bounds__(256) void k_cls(
    const float* __restrict__ h, const float* __restrict__ Wc,
    const float* __restrict__ bc, float* __restrict__ out) {
  int t = threadIdx.x;
  int lane = t & 63;
  int v = blockIdx.x * 4 + (t >> 6);
  if (v >= N_NODES) return;
  float p = h[v * 128 + lane] * Wc[lane] + h[v * 128 + 64 + lane] * Wc[64 + lane];
#pragma unroll
  for (int off = 32; off > 0; off >>= 1) p += __shfl_down(p, off);
  if (lane == 0) out[v] = 1.f / (1.f + expf(-(p + bc[0])));
}

// ---------------------------------------------------------------------------
extern "C" void kernel_launch(void* const* d_in, const int* in_sizes, int n_in,
                              void* d_out, int out_size, void* d_ws, size_t ws_size,
                              hipStream_t stream) {
  const float* x     = (const float*)d_in[0];
  const int*   eidx  = (const int*)d_in[1];
  const int*   uid   = (const int*)d_in[2];
  const int*   lid   = (const int*)d_in[3];
  const float* timef = (const float*)d_in[4];
  const float* utab  = (const float*)d_in[5];
  const float* ltab  = (const float*)d_in[6];
  const float* Wt    = (const float*)d_in[7];
  const float* bt    = (const float*)d_in[8];
  const float* W1l   = (const float*)d_in[9];
  const float* b1    = (const float*)d_in[10];
  const float* W1r   = (const float*)d_in[11];
  const float* W2l   = (const float*)d_in[12];
  const float* b2    = (const float*)d_in[13];
  const float* W2r   = (const float*)d_in[14];
  const float* Wc    = (const float*)d_in[15];
  const float* bc    = (const float*)d_in[16];
  float* out = (float*)d_out;

  const int E = in_sizes[1] / 2;
  const int* src = eidx;
  const int* dst = eidx + E;

  char* ws = (char*)d_ws;
  size_t off = 0;
  auto alloc = [&](size_t bytes) -> void* {
    void* p = ws + off;
    off += (bytes + 255) & ~(size_t)255;
    return p;
  };
  const size_t HBYTES = (size_t)N_NODES * 128 * sizeof(float);
  float* h0      = (float*)alloc(HBYTES);
  float* h1      = (float*)alloc(HBYTES);
  float* agg     = (float*)alloc(HBYTES);     // aliased as bdata during build
  int*   row_ptr = (int*)alloc((size_t)(N_NODES + 1) * 4);
  int*   col     = (int*)alloc((size_t)E * 4);
  int*   bcnt    = (int*)alloc((size_t)NB * 16 * 4);  // padded: 1 counter/line
  int*   bbase   = (int*)alloc((size_t)NB * 4);
  unsigned* bdata = (unsigned*)agg;  // NB*CAP*4 = 12.8MB < 51.2MB, dead after build
  (void)ws_size; (void)n_in; (void)out_size;

  // ---- embed + bucketed CSR build ----
  hipMemsetAsync(bcnt, 0, (size_t)NB * 16 * 4, stream);
  k_embed<<<(N_NODES + 1) / 2, 256, 0, stream>>>(x, uid, lid, timef, utab, ltab, Wt, bt, h0);
  k_bucket<<<(E + 255) / 256, 256, 0, stream>>>(src, dst, bcnt, bdata, E);
  k_bscan<<<1, 1024, 0, stream>>>(bcnt, bbase, row_ptr);
  k_bfill<<<NB, 256, 0, stream>>>(bcnt, bbase, bdata, row_ptr, col);

  // ---- layer 1 ----
  k_agg<<<N_NODES, 128, 0, stream>>>(h0, row_ptr, col, agg);
  k_gemm<<<(N_NODES + 63) / 64, 256, 0, stream>>>(agg, h0, W1l, W1r, b1, h1);

  // ---- layer 2 (h2 reuses h0 buffer) ----
  k_agg<<<N_NODES, 128, 0, stream>>>(h1, row_ptr, col, agg);
  k_gemm<<<(N_NODES + 63) / 64, 256, 0, stream>>>(agg, h1, W2l, W2r, b2, h0);

  // ---- classifier ----
  k_cls<<<(N_NODES + 3) / 4, 256, 0, stream>>>(h0, Wc, bc, out);
}

// Round 3
// 663.068 us; speedup vs baseline: 1.2075x; 1.0697x over previous
//
#include <hip/hip_runtime.h>
#include <math.h>

#define N_NODES 100000
#define HID 128
#define NB 782          // ceil(N_NODES / 128) buckets, 128 dst nodes each
#define CAP 4096        // per-bucket edge capacity (mean 2046, sigma ~45)

// ---------------------------------------------------------------------------
// Embedding/concat: h0 = [x(64) | user_emb(32) | loc_emb(16) | time@Wt+bt(16)]
// ---------------------------------------------------------------------------
__global__ __launch_bounds__(256) void k_embed(
    const float* __restrict__ x, const int* __restrict__ uid,
    const int* __restrict__ lid, const float* __restrict__ timef,
    const float* __restrict__ utab, const float* __restrict__ ltab,
    const float* __restrict__ Wt, const float* __restrict__ bt,
    float* __restrict__ h0) {
  int t = threadIdx.x;
  int v = blockIdx.x * 2 + (t >> 7);
  int f = t & 127;
  if (v >= N_NODES) return;
  float val;
  if (f < 64) {
    val = x[v * 64 + f];
  } else if (f < 96) {
    val = utab[uid[v] * 32 + (f - 64)];
  } else if (f < 112) {
    val = ltab[lid[v] * 16 + (f - 96)];
  } else {
    int c = f - 112;
    float acc = bt[c];
#pragma unroll
    for (int j = 0; j < 4; ++j) acc += timef[v * 4 + j] * Wt[j * 16 + c];
    val = acc;
  }
  h0[v * 128 + f] = val;
}

// ---------------------------------------------------------------------------
// Bucketed CSR build (round-2 design, unchanged: ~60us total)
// ---------------------------------------------------------------------------
__global__ __launch_bounds__(256) void k_bucket(
    const int* __restrict__ src, const int* __restrict__ dst,
    int* __restrict__ bcnt, unsigned* __restrict__ bdata, int E) {
  int e = blockIdx.x * 256 + threadIdx.x;
  if (e >= E) return;
  int d = dst[e];
  int s = src[e];
  int b = d >> 7;
  int pos = atomicAdd(&bcnt[b * 16], 1);
  if (pos < CAP) bdata[(size_t)b * CAP + pos] = ((unsigned)s << 7) | (unsigned)(d & 127);
}

__global__ __launch_bounds__(1024) void k_bscan(
    const int* __restrict__ bcnt, int* __restrict__ bbase,
    int* __restrict__ row_ptr) {
  __shared__ int s[1024];
  int t = threadIdx.x;
  int c = (t < NB) ? min(bcnt[t * 16], CAP) : 0;
  s[t] = c;
  __syncthreads();
  for (int off = 1; off < 1024; off <<= 1) {
    int add = (t >= off) ? s[t - off] : 0;
    __syncthreads();
    s[t] += add;
    __syncthreads();
  }
  if (t < NB) bbase[t] = s[t] - c;
  if (t == NB - 1) row_ptr[N_NODES] = s[t];
}

__global__ __launch_bounds__(256) void k_bfill(
    const int* __restrict__ bcnt, const int* __restrict__ bbase,
    const unsigned* __restrict__ bdata, int* __restrict__ row_ptr,
    int* __restrict__ col) {
  __shared__ unsigned sdata[3072];
  __shared__ int lcnt[128];
  __shared__ int loff[128];
  int b = blockIdx.x;
  int t = threadIdx.x;
  int cnt = min(bcnt[b * 16], CAP);
  int base = bbase[b];
  if (t < 128) lcnt[t] = 0;
  __syncthreads();
  const unsigned* bd = bdata + (size_t)b * CAP;
  for (int i = t; i < cnt; i += 256) {
    unsigned v = bd[i];
    if (i < 3072) sdata[i] = v;
    atomicAdd(&lcnt[v & 127u], 1);
  }
  __syncthreads();
  if (t < 128) loff[t] = lcnt[t];
  __syncthreads();
  for (int off = 1; off < 128; off <<= 1) {
    int add = 0;
    if (t < 128 && t >= off) add = loff[t - off];
    __syncthreads();
    if (t < 128) loff[t] += add;
    __syncthreads();
  }
  int node0 = b * 128;
  if (t < 128) {
    int excl = loff[t] - lcnt[t];
    if (node0 + t < N_NODES) row_ptr[node0 + t] = base + excl;
    lcnt[t] = excl;
  }
  __syncthreads();
  for (int i = t; i < cnt; i += 256) {
    unsigned v = (i < 3072) ? sdata[i] : bd[i];
    int pos = base + atomicAdd(&lcnt[v & 127u], 1);
    col[pos] = (int)(v >> 7);
  }
}

// ---------------------------------------------------------------------------
// Mean aggregation, float4: half-wave (32 lanes) per node, 8 nodes/block.
// Each lane owns one float4 column; 4 independent 1KB row-loads in flight.
// ---------------------------------------------------------------------------
__global__ __launch_bounds__(256) void k_agg(
    const float* __restrict__ h, const int* __restrict__ rp,
    const int* __restrict__ col, float* __restrict__ agg) {
  int t = threadIdx.x;
  int v = blockIdx.x * 8 + (t >> 5);
  int q = t & 31;
  if (v >= N_NODES) return;
  int s0 = rp[v], s1 = rp[v + 1];
  const float4* h4 = (const float4*)h;
  float4 acc = make_float4(0.f, 0.f, 0.f, 0.f);
  int j = s0;
  for (; j + 4 <= s1; j += 4) {
    int c0 = col[j], c1 = col[j + 1], c2 = col[j + 2], c3 = col[j + 3];
    float4 r0 = h4[(size_t)c0 * 32 + q];
    float4 r1 = h4[(size_t)c1 * 32 + q];
    float4 r2 = h4[(size_t)c2 * 32 + q];
    float4 r3 = h4[(size_t)c3 * 32 + q];
    acc.x += (r0.x + r1.x) + (r2.x + r3.x);
    acc.y += (r0.y + r1.y) + (r2.y + r3.y);
    acc.z += (r0.z + r1.z) + (r2.z + r3.z);
    acc.w += (r0.w + r1.w) + (r2.w + r3.w);
  }
  for (; j < s1; ++j) {
    float4 r = h4[(size_t)col[j] * 32 + q];
    acc.x += r.x; acc.y += r.y; acc.z += r.z; acc.w += r.w;
  }
  int deg = s1 - s0;
  float inv = 1.f / (float)(deg > 0 ? deg : 1);
  acc.x *= inv; acc.y *= inv; acc.z *= inv; acc.w *= inv;
  ((float4*)agg)[(size_t)v * 32 + q] = acc;
}

// ---------------------------------------------------------------------------
// Fused dual GEMM + bias + ReLU (+ optional fused classifier):
//   hout[v] = relu(agg[v]@Wl + hin[v]@Wr + b)
//   if CLS:  out[v] = sigmoid(hout[v] . Wc + bc)   (hout not materialized)
// 128 nodes/block, 256 threads, 8x8 acc/thread, BK=32, 8 k-chunks.
// LDS layouts (conflict-free):
//   As[k][col], col = node ^ ((k>>2 & 3)<<3)  -> <=2-way on write & read
//   Ws even/odd float4-chunk split: w0 chunks at [0,64), w1 at [64,128)
// A-chunk for c+1 prefetched into regs during compute of chunk c.
// ---------------------------------------------------------------------------
template <bool CLS>
__global__ __launch_bounds__(256, 4) void k_gemm(
    const float* __restrict__ agg, const float* __restrict__ hin,
    const float* __restrict__ Wl, const float* __restrict__ Wr,
    const float* __restrict__ bias, float* __restrict__ hout,
    const float* __restrict__ Wc, const float* __restrict__ bc,
    float* __restrict__ out) {
  __shared__ float As[32 * 128];
  __shared__ float Ws[32 * 128];
  __shared__ float zred[128];
  int t = threadIdx.x;
  int fg = t & 15;   // feats fg*8 .. fg*8+7
  int ng = t >> 4;   // nodes ng*8 .. ng*8+7
  int mbase = blockIdx.x * 128;

  float acc[8][8];
#pragma unroll
  for (int i = 0; i < 8; ++i)
#pragma unroll
    for (int j = 0; j < 8; ++j) acc[i][j] = 0.f;

  float4 Areg[4];
  // prefetch A chunk 0
#pragma unroll
  for (int s = 0; s < 4; ++s) {
    int i = t + s * 256;
    int node = i >> 3, q = i & 7;
    int gn = mbase + node;
    Areg[s] = (gn < N_NODES) ? *(const float4*)&agg[(size_t)gn * 128 + q * 4]
                             : make_float4(0.f, 0.f, 0.f, 0.f);
  }

  for (int c = 0; c < 8; ++c) {
    const float* Wp = (c < 4) ? Wl : Wr;
    int ko = (c & 3) * 32;
    __syncthreads();
    // stage A regs -> As (swizzled)
#pragma unroll
    for (int s = 0; s < 4; ++s) {
      int i = t + s * 256;
      int node = i >> 3, q = i & 7;
      int colx = node ^ ((q & 3) << 3);
      float av[4] = {Areg[s].x, Areg[s].y, Areg[s].z, Areg[s].w};
#pragma unroll
      for (int j = 0; j < 4; ++j) As[(q * 4 + j) * 128 + colx] = av[j];
    }
    // stage W chunk -> Ws (even/odd split), straight from global (L2-hot)
#pragma unroll
    for (int s = 0; s < 4; ++s) {
      int i = t + s * 256;
      int c2 = i & 31, r = i >> 5;
      float4 wv = *(const float4*)&Wp[ko * 128 + i * 4];
      *(float4*)&Ws[r * 128 + (((c2 >> 1) + (c2 & 1) * 16) << 2)] = wv;
    }
    __syncthreads();
    // prefetch A for next chunk
    if (c < 7) {
      int cn = c + 1;
      const float* Ap = (cn < 4) ? agg : hin;
      int kon = (cn & 3) * 32;
#pragma unroll
      for (int s = 0; s < 4; ++s) {
        int i = t + s * 256;
        int node = i >> 3, q = i & 7;
        int gn = mbase + node;
        Areg[s] = (gn < N_NODES) ? *(const float4*)&Ap[(size_t)gn * 128 + kon + q * 4]
                                 : make_float4(0.f, 0.f, 0.f, 0.f);
      }
    }
    // compute
#pragma unroll 2
    for (int kk = 0; kk < 32; ++kk) {
      int cbase = (ng * 8) ^ (((kk >> 2) & 3) << 3);
      const float4 a0 = *(const float4*)&As[kk * 128 + cbase];
      const float4 a1 = *(const float4*)&As[kk * 128 + cbase + 4];
      const float4 w0 = *(const float4*)&Ws[kk * 128 + fg * 4];
      const float4 w1 = *(const float4*)&Ws[kk * 128 + 64 + fg * 4];
      float a_[8] = {a0.x, a0.y, a0.z, a0.w, a1.x, a1.y, a1.z, a1.w};
      float w_[8] = {w0.x, w0.y, w0.z, w0.w, w1.x, w1.y, w1.z, w1.w};
#pragma unroll
      for (int i = 0; i < 8; ++i)
#pragma unroll
        for (int j = 0; j < 8; ++j) acc[i][j] += a_[i] * w_[j];
    }
  }

  float bv[8];
#pragma unroll
  for (int j = 0; j < 8; ++j) bv[j] = bias[fg * 8 + j];

  if (!CLS) {
#pragma unroll
    for (int i = 0; i < 8; ++i) {
      int node = mbase + ng * 8 + i;
      if (node < N_NODES) {
        float4 o0, o1;
        o0.x = fmaxf(acc[i][0] + bv[0], 0.f);
        o0.y = fmaxf(acc[i][1] + bv[1], 0.f);
        o0.z = fmaxf(acc[i][2] + bv[2], 0.f);
        o0.w = fmaxf(acc[i][3] + bv[3], 0.f);
        o1.x = fmaxf(acc[i][4] + bv[4], 0.f);
        o1.y = fmaxf(acc[i][5] + bv[5], 0.f);
        o1.z = fmaxf(acc[i][6] + bv[6], 0.f);
        o1.w = fmaxf(acc[i][7] + bv[7], 0.f);
        *(float4*)&hout[(size_t)node * 128 + fg * 8] = o0;
        *(float4*)&hout[(size_t)node * 128 + fg * 8 + 4] = o1;
      }
    }
  } else {
    float wc[8];
#pragma unroll
    for (int j = 0; j < 8; ++j) wc[j] = Wc[fg * 8 + j];
#pragma unroll
    for (int i = 0; i < 8; ++i) {
      float p = 0.f;
#pragma unroll
      for (int j = 0; j < 8; ++j) p += fmaxf(acc[i][j] + bv[j], 0.f) * wc[j];
      // reduce over the 16 fg lanes (lane bits 0..3)
      p += __shfl_xor(p, 1);
      p += __shfl_xor(p, 2);
      p += __shfl_xor(p, 4);
      p += __shfl_xor(p, 8);
      if (fg == 0) zred[ng * 8 + i] = p;
    }
    __syncthreads();
    if (t < 128) {
      int node = mbase + t;
      if (node < N_NODES) out[node] = 1.f / (1.f + expf(-(zred[t] + bc[0])));
    }
  }
}

// ---------------------------------------------------------------------------
extern "C" void kernel_launch(void* const* d_in, const int* in_sizes, int n_in,
                              void* d_out, int out_size, void* d_ws, size_t ws_size,
                              hipStream_t stream) {
  const float* x     = (const float*)d_in[0];
  const int*   eidx  = (const int*)d_in[1];
  const int*   uid   = (const int*)d_in[2];
  const int*   lid   = (const int*)d_in[3];
  const float* timef = (const float*)d_in[4];
  const float* utab  = (const float*)d_in[5];
  const float* ltab  = (const float*)d_in[6];
  const float* Wt    = (const float*)d_in[7];
  const float* bt    = (const float*)d_in[8];
  const float* W1l   = (const float*)d_in[9];
  const float* b1    = (const float*)d_in[10];
  const float* W1r   = (const float*)d_in[11];
  const float* W2l   = (const float*)d_in[12];
  const float* b2    = (const float*)d_in[13];
  const float* W2r   = (const float*)d_in[14];
  const float* Wc    = (const float*)d_in[15];
  const float* bc    = (const float*)d_in[16];
  float* out = (float*)d_out;

  const int E = in_sizes[1] / 2;
  const int* src = eidx;
  const int* dst = eidx + E;

  char* ws = (char*)d_ws;
  size_t off = 0;
  auto alloc = [&](size_t bytes) -> void* {
    void* p = ws + off;
    off += (bytes + 255) & ~(size_t)255;
    return p;
  };
  const size_t HBYTES = (size_t)N_NODES * 128 * sizeof(float);
  float* h0      = (float*)alloc(HBYTES);
  float* h1      = (float*)alloc(HBYTES);
  float* agg     = (float*)alloc(HBYTES);     // aliased as bdata during build
  int*   row_ptr = (int*)alloc((size_t)(N_NODES + 1) * 4);
  int*   col     = (int*)alloc((size_t)E * 4);
  int*   bcnt    = (int*)alloc((size_t)NB * 16 * 4);
  int*   bbase   = (int*)alloc((size_t)NB * 4);
  unsigned* bdata = (unsigned*)agg;  // 12.8MB < 51.2MB, dead after build
  (void)ws_size; (void)n_in; (void)out_size;

  // ---- embed + bucketed CSR build ----
  hipMemsetAsync(bcnt, 0, (size_t)NB * 16 * 4, stream);
  k_embed<<<(N_NODES + 1) / 2, 256, 0, stream>>>(x, uid, lid, timef, utab, ltab, Wt, bt, h0);
  k_bucket<<<(E + 255) / 256, 256, 0, stream>>>(src, dst, bcnt, bdata, E);
  k_bscan<<<1, 1024, 0, stream>>>(bcnt, bbase, row_ptr);
  k_bfill<<<NB, 256, 0, stream>>>(bcnt, bbase, bdata, row_ptr, col);

  // ---- layer 1 ----
  k_agg<<<(N_NODES + 7) / 8, 256, 0, stream>>>(h0, row_ptr, col, agg);
  k_gemm<false><<<(N_NODES + 127) / 128, 256, 0, stream>>>(
      agg, h0, W1l, W1r, b1, h1, nullptr, nullptr, nullptr);

  // ---- layer 2 + fused classifier ----
  k_agg<<<(N_NODES + 7) / 8, 256, 0, stream>>>(h1, row_ptr, col, agg);
  k_gemm<true><<<(N_NODES + 127) / 128, 256, 0, stream>>>(
      agg, h1, W2l, W2r, b2, nullptr, Wc, bc, out);
}

// Round 4
// 425.476 us; speedup vs baseline: 1.8818x; 1.5584x over previous
//
#include <hip/hip_runtime.h>
#include <math.h>

#define N_NODES 100000
#define HID 128
#define NB 782          // ceil(N_NODES / 128) buckets, 128 dst nodes each
#define CAP 4096        // per-bucket edge capacity (mean 2046, sigma ~45)

typedef __attribute__((ext_vector_type(8))) short bf16x8;
typedef __attribute__((ext_vector_type(4))) float f32x4;

__device__ __forceinline__ unsigned short f2bf(float f) {
  union { float f; unsigned u; } v; v.f = f;
  unsigned r = v.u + 0x7FFFu + ((v.u >> 16) & 1u);  // RNE
  return (unsigned short)(r >> 16);
}
__device__ __forceinline__ unsigned packbf(float lo, float hi) {
  return (unsigned)f2bf(lo) | ((unsigned)f2bf(hi) << 16);
}
__device__ __forceinline__ void acc_add(float* a, uint4 u) {
  unsigned w[4] = {u.x, u.y, u.z, u.w};
#pragma unroll
  for (int i = 0; i < 4; ++i) {
    union { unsigned u; float f; } lo, hi;
    lo.u = w[i] << 16;
    hi.u = w[i] & 0xFFFF0000u;
    a[2 * i] += lo.f;
    a[2 * i + 1] += hi.f;
  }
}

// ---------------------------------------------------------------------------
// Embedding/concat -> bf16 h0
// ---------------------------------------------------------------------------
__global__ __launch_bounds__(256) void k_embed(
    const float* __restrict__ x, const int* __restrict__ uid,
    const int* __restrict__ lid, const float* __restrict__ timef,
    const float* __restrict__ utab, const float* __restrict__ ltab,
    const float* __restrict__ Wt, const float* __restrict__ bt,
    unsigned short* __restrict__ h0) {
  int t = threadIdx.x;
  int v = blockIdx.x * 2 + (t >> 7);
  int f = t & 127;
  if (v >= N_NODES) return;
  float val;
  if (f < 64) {
    val = x[v * 64 + f];
  } else if (f < 96) {
    val = utab[uid[v] * 32 + (f - 64)];
  } else if (f < 112) {
    val = ltab[lid[v] * 16 + (f - 96)];
  } else {
    int c = f - 112;
    float acc = bt[c];
#pragma unroll
    for (int j = 0; j < 4; ++j) acc += timef[v * 4 + j] * Wt[j * 16 + c];
    val = acc;
  }
  h0[(size_t)v * 128 + f] = f2bf(val);
}

// ---------------------------------------------------------------------------
// Weight prep: 4 matrices W[k][f] fp32 -> WT[f][k] bf16 (each 128x128)
// ---------------------------------------------------------------------------
__global__ __launch_bounds__(256) void k_wprep(
    const float* __restrict__ W1l, const float* __restrict__ W1r,
    const float* __restrict__ W2l, const float* __restrict__ W2r,
    unsigned short* __restrict__ WT) {
  int idx = blockIdx.x * 256 + threadIdx.x;  // 65536 total
  int m = idx >> 14;
  int rem = idx & 16383;
  int k = rem >> 7;
  int f = rem & 127;
  const float* W = (m == 0) ? W1l : (m == 1) ? W1r : (m == 2) ? W2l : W2r;
  WT[m * 16384 + f * 128 + k] = f2bf(W[k * 128 + f]);
}

// ---------------------------------------------------------------------------
// Bucketed CSR build (round-2 design, unchanged)
// ---------------------------------------------------------------------------
__global__ __launch_bounds__(256) void k_bucket(
    const int* __restrict__ src, const int* __restrict__ dst,
    int* __restrict__ bcnt, unsigned* __restrict__ bdata, int E) {
  int e = blockIdx.x * 256 + threadIdx.x;
  if (e >= E) return;
  int d = dst[e];
  int s = src[e];
  int b = d >> 7;
  int pos = atomicAdd(&bcnt[b * 16], 1);
  if (pos < CAP) bdata[(size_t)b * CAP + pos] = ((unsigned)s << 7) | (unsigned)(d & 127);
}

__global__ __launch_bounds__(1024) void k_bscan(
    const int* __restrict__ bcnt, int* __restrict__ bbase,
    int* __restrict__ row_ptr) {
  __shared__ int s[1024];
  int t = threadIdx.x;
  int c = (t < NB) ? min(bcnt[t * 16], CAP) : 0;
  s[t] = c;
  __syncthreads();
  for (int off = 1; off < 1024; off <<= 1) {
    int add = (t >= off) ? s[t - off] : 0;
    __syncthreads();
    s[t] += add;
    __syncthreads();
  }
  if (t < NB) bbase[t] = s[t] - c;
  if (t == NB - 1) row_ptr[N_NODES] = s[t];
}

__global__ __launch_bounds__(256) void k_bfill(
    const int* __restrict__ bcnt, const int* __restrict__ bbase,
    const unsigned* __restrict__ bdata, int* __restrict__ row_ptr,
    int* __restrict__ col) {
  __shared__ unsigned sdata[3072];
  __shared__ int lcnt[128];
  __shared__ int loff[128];
  int b = blockIdx.x;
  int t = threadIdx.x;
  int cnt = min(bcnt[b * 16], CAP);
  int base = bbase[b];
  if (t < 128) lcnt[t] = 0;
  __syncthreads();
  const unsigned* bd = bdata + (size_t)b * CAP;
  for (int i = t; i < cnt; i += 256) {
    unsigned v = bd[i];
    if (i < 3072) sdata[i] = v;
    atomicAdd(&lcnt[v & 127u], 1);
  }
  __syncthreads();
  if (t < 128) loff[t] = lcnt[t];
  __syncthreads();
  for (int off = 1; off < 128; off <<= 1) {
    int add = 0;
    if (t < 128 && t >= off) add = loff[t - off];
    __syncthreads();
    if (t < 128) loff[t] += add;
    __syncthreads();
  }
  int node0 = b * 128;
  if (t < 128) {
    int excl = loff[t] - lcnt[t];
    if (node0 + t < N_NODES) row_ptr[node0 + t] = base + excl;
    lcnt[t] = excl;
  }
  __syncthreads();
  for (int i = t; i < cnt; i += 256) {
    unsigned v = (i < 3072) ? sdata[i] : bd[i];
    int pos = base + atomicAdd(&lcnt[v & 127u], 1);
    col[pos] = (int)(v >> 7);
  }
}

// ---------------------------------------------------------------------------
// Mean aggregation over bf16 rows: 16 lanes/node (16B segment each),
// 16 nodes/block. fp32 accumulate, RNE bf16 store.
// ---------------------------------------------------------------------------
__global__ __launch_bounds__(256) void k_agg(
    const unsigned short* __restrict__ h, const int* __restrict__ rp,
    const int* __restrict__ col, unsigned short* __restrict__ agg) {
  int t = threadIdx.x;
  int v = blockIdx.x * 16 + (t >> 4);
  int q = t & 15;
  if (v >= N_NODES) return;
  int s0 = rp[v], s1 = rp[v + 1];
  const uint4* h4 = (const uint4*)h;  // 16 uint4 per 256B row
  float acc[8] = {0.f, 0.f, 0.f, 0.f, 0.f, 0.f, 0.f, 0.f};
  int j = s0;
  for (; j + 4 <= s1; j += 4) {
    uint4 r0 = h4[(size_t)col[j] * 16 + q];
    uint4 r1 = h4[(size_t)col[j + 1] * 16 + q];
    uint4 r2 = h4[(size_t)col[j + 2] * 16 + q];
    uint4 r3 = h4[(size_t)col[j + 3] * 16 + q];
    acc_add(acc, r0);
    acc_add(acc, r1);
    acc_add(acc, r2);
    acc_add(acc, r3);
  }
  for (; j < s1; ++j) acc_add(acc, h4[(size_t)col[j] * 16 + q]);
  int deg = s1 - s0;
  float inv = 1.f / (float)(deg > 0 ? deg : 1);
  uint4 o;
  o.x = packbf(acc[0] * inv, acc[1] * inv);
  o.y = packbf(acc[2] * inv, acc[3] * inv);
  o.z = packbf(acc[4] * inv, acc[5] * inv);
  o.w = packbf(acc[6] * inv, acc[7] * inv);
  ((uint4*)agg)[(size_t)v * 16 + q] = o;
}

// ---------------------------------------------------------------------------
// MFMA bf16 dual GEMM + bias + ReLU (+ fused classifier for CLS):
//   z[v] = agg[v]@Wl + hin[v]@Wr + b ; hout = relu(z) (bf16)  or
//   out[v] = sigmoid(relu(z) . Wc + bc)
// Block: 128 nodes x 128 feats, 4 waves (2x2), 4x4 16x16x32 frags per wave.
// K staged in 4 chunks of 64 (agg k0, agg k64, hin k0, hin k64).
// LDS rows padded to 72 bf16 (144B): ds_read_b128 <=2-way (free).
// WT is [f][k] so B-operand reads are contiguous in k.
// ---------------------------------------------------------------------------
template <bool CLS>
__global__ __launch_bounds__(256, 3) void k_gemm(
    const unsigned short* __restrict__ agg, const unsigned short* __restrict__ hin,
    const unsigned short* __restrict__ WlT, const unsigned short* __restrict__ WrT,
    const float* __restrict__ bias, unsigned short* __restrict__ hout,
    const float* __restrict__ Wc, const float* __restrict__ bc,
    float* __restrict__ out) {
  __shared__ unsigned short As[128 * 72];
  __shared__ unsigned short Ws[128 * 72];
  __shared__ float zred[2][128];
  int t = threadIdx.x;
  int lane = t & 63;
  int wave = t >> 6;
  int wm = (wave & 1) * 64;   // node offset of wave
  int wn = (wave >> 1) * 64;  // feat offset of wave
  int l15 = lane & 15;
  int quad = lane >> 4;
  int mbase = blockIdx.x * 128;

  f32x4 acc[4][4];
#pragma unroll
  for (int i = 0; i < 4; ++i)
#pragma unroll
    for (int j = 0; j < 4; ++j) acc[i][j] = (f32x4){0.f, 0.f, 0.f, 0.f};

  int r = t >> 1, seg = t & 1;  // staging: thread owns 64B of row r
  int gn = mbase + r;

  for (int c = 0; c < 4; ++c) {
    const unsigned short* Ap = (c < 2) ? agg : hin;
    const unsigned short* Wp = (c < 2) ? WlT : WrT;
    int koff = (c & 1) * 64;
    // global loads (4x16B each for A and W)
    uint4 av[4], wv[4];
    if (gn < N_NODES) {
      const uint4* ap = (const uint4*)(Ap + (size_t)gn * 128 + koff + seg * 32);
#pragma unroll
      for (int i = 0; i < 4; ++i) av[i] = ap[i];
    } else {
#pragma unroll
      for (int i = 0; i < 4; ++i) av[i] = make_uint4(0, 0, 0, 0);
    }
    const uint4* wp = (const uint4*)(Wp + (size_t)r * 128 + koff + seg * 32);
#pragma unroll
    for (int i = 0; i < 4; ++i) wv[i] = wp[i];
    __syncthreads();  // protect previous iteration's reads
#pragma unroll
    for (int i = 0; i < 4; ++i) {
      *(uint4*)&As[r * 72 + seg * 32 + i * 8] = av[i];
      *(uint4*)&Ws[r * 72 + seg * 32 + i * 8] = wv[i];
    }
    __syncthreads();
#pragma unroll
    for (int ks = 0; ks < 2; ++ks) {
      int kb = ks * 32 + quad * 8;
      bf16x8 af[4], bfr[4];
#pragma unroll
      for (int im = 0; im < 4; ++im)
        af[im] = *(const bf16x8*)&As[(wm + im * 16 + l15) * 72 + kb];
#pragma unroll
      for (int jn = 0; jn < 4; ++jn)
        bfr[jn] = *(const bf16x8*)&Ws[(wn + jn * 16 + l15) * 72 + kb];
#pragma unroll
      for (int im = 0; im < 4; ++im)
#pragma unroll
        for (int jn = 0; jn < 4; ++jn)
          acc[im][jn] = __builtin_amdgcn_mfma_f32_16x16x32_bf16(
              af[im], bfr[jn], acc[im][jn], 0, 0, 0);
    }
  }

  if (!CLS) {
    float bv[4];
#pragma unroll
    for (int jn = 0; jn < 4; ++jn) bv[jn] = bias[wn + jn * 16 + l15];
#pragma unroll
    for (int im = 0; im < 4; ++im) {
#pragma unroll
      for (int rr = 0; rr < 4; ++rr) {
        int node = mbase + wm + im * 16 + quad * 4 + rr;
        if (node < N_NODES) {
#pragma unroll
          for (int jn = 0; jn < 4; ++jn) {
            int f = wn + jn * 16 + l15;
            float zv = fmaxf(acc[im][jn][rr] + bv[jn], 0.f);
            hout[(size_t)node * 128 + f] = f2bf(zv);
          }
        }
      }
    }
  } else {
    float bv[4], wcv[4];
#pragma unroll
    for (int jn = 0; jn < 4; ++jn) {
      bv[jn] = bias[wn + jn * 16 + l15];
      wcv[jn] = Wc[wn + jn * 16 + l15];
    }
#pragma unroll
    for (int im = 0; im < 4; ++im) {
#pragma unroll
      for (int rr = 0; rr < 4; ++rr) {
        float p = 0.f;
#pragma unroll
        for (int jn = 0; jn < 4; ++jn)
          p += fmaxf(acc[im][jn][rr] + bv[jn], 0.f) * wcv[jn];
        p += __shfl_xor(p, 1);
        p += __shfl_xor(p, 2);
        p += __shfl_xor(p, 4);
        p += __shfl_xor(p, 8);
        if (l15 == 0) zred[wave >> 1][wm + im * 16 + quad * 4 + rr] = p;
      }
    }
    __syncthreads();
    if (t < 128) {
      int node = mbase + t;
      if (node < N_NODES)
        out[node] = 1.f / (1.f + expf(-(zred[0][t] + zred[1][t] + bc[0])));
    }
  }
}

// ---------------------------------------------------------------------------
extern "C" void kernel_launch(void* const* d_in, const int* in_sizes, int n_in,
                              void* d_out, int out_size, void* d_ws, size_t ws_size,
                              hipStream_t stream) {
  const float* x     = (const float*)d_in[0];
  const int*   eidx  = (const int*)d_in[1];
  const int*   uid   = (const int*)d_in[2];
  const int*   lid   = (const int*)d_in[3];
  const float* timef = (const float*)d_in[4];
  const float* utab  = (const float*)d_in[5];
  const float* ltab  = (const float*)d_in[6];
  const float* Wt    = (const float*)d_in[7];
  const float* bt    = (const float*)d_in[8];
  const float* W1l   = (const float*)d_in[9];
  const float* b1    = (const float*)d_in[10];
  const float* W1r   = (const float*)d_in[11];
  const float* W2l   = (const float*)d_in[12];
  const float* b2    = (const float*)d_in[13];
  const float* W2r   = (const float*)d_in[14];
  const float* Wc    = (const float*)d_in[15];
  const float* bc    = (const float*)d_in[16];
  float* out = (float*)d_out;

  const int E = in_sizes[1] / 2;
  const int* src = eidx;
  const int* dst = eidx + E;

  char* ws = (char*)d_ws;
  size_t off = 0;
  auto alloc = [&](size_t bytes) -> void* {
    void* p = ws + off;
    off += (bytes + 255) & ~(size_t)255;
    return p;
  };
  const size_t HBYTES = (size_t)N_NODES * 128 * sizeof(unsigned short);  // 25.6MB
  unsigned short* h0  = (unsigned short*)alloc(HBYTES);
  unsigned short* h1  = (unsigned short*)alloc(HBYTES);
  unsigned short* agg = (unsigned short*)alloc(HBYTES);  // aliased as bdata in build
  unsigned short* WT  = (unsigned short*)alloc(4 * 16384 * sizeof(unsigned short));
  int* row_ptr = (int*)alloc((size_t)(N_NODES + 1) * 4);
  int* col     = (int*)alloc((size_t)E * 4);
  int* bcnt    = (int*)alloc((size_t)NB * 16 * 4);
  int* bbase   = (int*)alloc((size_t)NB * 4);
  unsigned* bdata = (unsigned*)agg;  // 12.8MB < 25.6MB, dead after build
  (void)ws_size; (void)n_in; (void)out_size;

  // ---- embed + weight prep + bucketed CSR build ----
  hipMemsetAsync(bcnt, 0, (size_t)NB * 16 * 4, stream);
  k_embed<<<(N_NODES + 1) / 2, 256, 0, stream>>>(x, uid, lid, timef, utab, ltab, Wt, bt, h0);
  k_wprep<<<256, 256, 0, stream>>>(W1l, W1r, W2l, W2r, WT);
  k_bucket<<<(E + 255) / 256, 256, 0, stream>>>(src, dst, bcnt, bdata, E);
  k_bscan<<<1, 1024, 0, stream>>>(bcnt, bbase, row_ptr);
  k_bfill<<<NB, 256, 0, stream>>>(bcnt, bbase, bdata, row_ptr, col);

  // ---- layer 1 ----
  k_agg<<<(N_NODES + 15) / 16, 256, 0, stream>>>(h0, row_ptr, col, agg);
  k_gemm<false><<<(N_NODES + 127) / 128, 256, 0, stream>>>(
      agg, h0, WT, WT + 16384, b1, h1, nullptr, nullptr, nullptr);

  // ---- layer 2 + fused classifier ----
  k_agg<<<(N_NODES + 15) / 16, 256, 0, stream>>>(h1, row_ptr, col, agg);
  k_gemm<true><<<(N_NODES + 127) / 128, 256, 0, stream>>>(
      agg, h1, WT + 32768, WT + 49152, b2, nullptr, Wc, bc, out);
}

// Round 5
// 372.755 us; speedup vs baseline: 2.1479x; 1.1414x over previous
//
#include <hip/hip_runtime.h>
#include <math.h>

#define N_NODES 100000
#define HID 128
#define NB 782          // ceil(N_NODES / 128) buckets, 128 dst nodes each
#define CAP 4096        // per-bucket edge capacity (mean 2046, sigma ~45)
#define BTILE 16384     // edges per block in k_bucket

typedef __attribute__((ext_vector_type(8))) short bf16x8;
typedef __attribute__((ext_vector_type(4))) float f32x4;

__device__ __forceinline__ unsigned short f2bf(float f) {
  union { float f; unsigned u; } v; v.f = f;
  unsigned r = v.u + 0x7FFFu + ((v.u >> 16) & 1u);  // RNE
  return (unsigned short)(r >> 16);
}
__device__ __forceinline__ unsigned packbf(float lo, float hi) {
  return (unsigned)f2bf(lo) | ((unsigned)f2bf(hi) << 16);
}
__device__ __forceinline__ void acc_add(float* a, uint4 u) {
  unsigned w[4] = {u.x, u.y, u.z, u.w};
#pragma unroll
  for (int i = 0; i < 4; ++i) {
    union { unsigned u; float f; } lo, hi;
    lo.u = w[i] << 16;
    hi.u = w[i] & 0xFFFF0000u;
    a[2 * i] += lo.f;
    a[2 * i + 1] += hi.f;
  }
}

// ---------------------------------------------------------------------------
// Embedding/concat -> bf16 h0
// ---------------------------------------------------------------------------
__global__ __launch_bounds__(256) void k_embed(
    const float* __restrict__ x, const int* __restrict__ uid,
    const int* __restrict__ lid, const float* __restrict__ timef,
    const float* __restrict__ utab, const float* __restrict__ ltab,
    const float* __restrict__ Wt, const float* __restrict__ bt,
    unsigned short* __restrict__ h0) {
  int t = threadIdx.x;
  int v = blockIdx.x * 2 + (t >> 7);
  int f = t & 127;
  if (v >= N_NODES) return;
  float val;
  if (f < 64) {
    val = x[v * 64 + f];
  } else if (f < 96) {
    val = utab[uid[v] * 32 + (f - 64)];
  } else if (f < 112) {
    val = ltab[lid[v] * 16 + (f - 96)];
  } else {
    int c = f - 112;
    float acc = bt[c];
#pragma unroll
    for (int j = 0; j < 4; ++j) acc += timef[v * 4 + j] * Wt[j * 16 + c];
    val = acc;
  }
  h0[(size_t)v * 128 + f] = f2bf(val);
}

// ---------------------------------------------------------------------------
// Weight prep: 4 matrices W[k][f] fp32 -> WT[f][k] bf16 (each 128x128)
// ---------------------------------------------------------------------------
__global__ __launch_bounds__(256) void k_wprep(
    const float* __restrict__ W1l, const float* __restrict__ W1r,
    const float* __restrict__ W2l, const float* __restrict__ W2r,
    unsigned short* __restrict__ WT) {
  int idx = blockIdx.x * 256 + threadIdx.x;  // 65536 total
  int m = idx >> 14;
  int rem = idx & 16383;
  int k = rem >> 7;
  int f = rem & 127;
  const float* W = (m == 0) ? W1l : (m == 1) ? W1r : (m == 2) ? W2l : W2r;
  WT[m * 16384 + f * 128 + k] = f2bf(W[k * 128 + f]);
}

// ---------------------------------------------------------------------------
// Bucketed CSR build, pass A (tile-local binning):
// per block: LDS histogram of 782 buckets -> 1 global atomicAdd per
// non-empty bucket to reserve a contiguous run -> scatter into runs.
// Write-back ~11MB instead of 82MB (contiguous ~84B runs per bucket/block).
// ---------------------------------------------------------------------------
__global__ __launch_bounds__(512) void k_bucket(
    const int* __restrict__ src, const int* __restrict__ dst,
    int* __restrict__ bcnt, unsigned* __restrict__ bdata, int E) {
  __shared__ int hcnt[NB];
  __shared__ int hbase[NB];
  int t = threadIdx.x;
  int e0 = blockIdx.x * BTILE;
  int e1 = min(e0 + BTILE, E);
  for (int i = t; i < NB; i += 512) hcnt[i] = 0;
  __syncthreads();
  for (int e = e0 + t; e < e1; e += 512) atomicAdd(&hcnt[dst[e] >> 7], 1);
  __syncthreads();
  for (int i = t; i < NB; i += 512) {
    int c = hcnt[i];
    hbase[i] = (c > 0) ? atomicAdd(&bcnt[i * 16], c) : 0;
    hcnt[i] = 0;  // becomes local cursor
  }
  __syncthreads();
  for (int e = e0 + t; e < e1; e += 512) {
    int d = dst[e];
    int s = src[e];
    int b = d >> 7;
    int pos = hbase[b] + atomicAdd(&hcnt[b], 1);
    if (pos < CAP) bdata[(size_t)b * CAP + pos] = ((unsigned)s << 7) | (unsigned)(d & 127);
  }
}

__global__ __launch_bounds__(1024) void k_bscan(
    const int* __restrict__ bcnt, int* __restrict__ bbase,
    int* __restrict__ row_ptr) {
  __shared__ int s[1024];
  int t = threadIdx.x;
  int c = (t < NB) ? min(bcnt[t * 16], CAP) : 0;
  s[t] = c;
  __syncthreads();
  for (int off = 1; off < 1024; off <<= 1) {
    int add = (t >= off) ? s[t - off] : 0;
    __syncthreads();
    s[t] += add;
    __syncthreads();
  }
  if (t < NB) bbase[t] = s[t] - c;
  if (t == NB - 1) row_ptr[N_NODES] = s[t];
}

__global__ __launch_bounds__(256) void k_bfill(
    const int* __restrict__ bcnt, const int* __restrict__ bbase,
    const unsigned* __restrict__ bdata, int* __restrict__ row_ptr,
    int* __restrict__ col) {
  __shared__ unsigned sdata[3072];
  __shared__ int lcnt[128];
  __shared__ int loff[128];
  int b = blockIdx.x;
  int t = threadIdx.x;
  int cnt = min(bcnt[b * 16], CAP);
  int base = bbase[b];
  if (t < 128) lcnt[t] = 0;
  __syncthreads();
  const unsigned* bd = bdata + (size_t)b * CAP;
  for (int i = t; i < cnt; i += 256) {
    unsigned v = bd[i];
    if (i < 3072) sdata[i] = v;
    atomicAdd(&lcnt[v & 127u], 1);
  }
  __syncthreads();
  if (t < 128) loff[t] = lcnt[t];
  __syncthreads();
  for (int off = 1; off < 128; off <<= 1) {
    int add = 0;
    if (t < 128 && t >= off) add = loff[t - off];
    __syncthreads();
    if (t < 128) loff[t] += add;
    __syncthreads();
  }
  int node0 = b * 128;
  if (t < 128) {
    int excl = loff[t] - lcnt[t];
    if (node0 + t < N_NODES) row_ptr[node0 + t] = base + excl;
    lcnt[t] = excl;
  }
  __syncthreads();
  for (int i = t; i < cnt; i += 256) {
    unsigned v = (i < 3072) ? sdata[i] : bd[i];
    int pos = base + atomicAdd(&lcnt[v & 127u], 1);
    col[pos] = (int)(v >> 7);
  }
}

// ---------------------------------------------------------------------------
// Mean aggregation over bf16 rows: 16 lanes/node, 16 nodes/block.
// ---------------------------------------------------------------------------
__global__ __launch_bounds__(256) void k_agg(
    const unsigned short* __restrict__ h, const int* __restrict__ rp,
    const int* __restrict__ col, unsigned short* __restrict__ agg) {
  int t = threadIdx.x;
  int v = blockIdx.x * 16 + (t >> 4);
  int q = t & 15;
  if (v >= N_NODES) return;
  int s0 = rp[v], s1 = rp[v + 1];
  const uint4* h4 = (const uint4*)h;  // 16 uint4 per 256B row
  float acc[8] = {0.f, 0.f, 0.f, 0.f, 0.f, 0.f, 0.f, 0.f};
  int j = s0;
  for (; j + 4 <= s1; j += 4) {
    uint4 r0 = h4[(size_t)col[j] * 16 + q];
    uint4 r1 = h4[(size_t)col[j + 1] * 16 + q];
    uint4 r2 = h4[(size_t)col[j + 2] * 16 + q];
    uint4 r3 = h4[(size_t)col[j + 3] * 16 + q];
    acc_add(acc, r0);
    acc_add(acc, r1);
    acc_add(acc, r2);
    acc_add(acc, r3);
  }
  for (; j < s1; ++j) acc_add(acc, h4[(size_t)col[j] * 16 + q]);
  int deg = s1 - s0;
  float inv = 1.f / (float)(deg > 0 ? deg : 1);
  uint4 o;
  o.x = packbf(acc[0] * inv, acc[1] * inv);
  o.y = packbf(acc[2] * inv, acc[3] * inv);
  o.z = packbf(acc[4] * inv, acc[5] * inv);
  o.w = packbf(acc[6] * inv, acc[7] * inv);
  ((uint4*)agg)[(size_t)v * 16 + q] = o;
}

// ---------------------------------------------------------------------------
// MFMA bf16 dual GEMM + bias + ReLU (+ fused classifier for CLS)
// ---------------------------------------------------------------------------
template <bool CLS>
__global__ __launch_bounds__(256, 3) void k_gemm(
    const unsigned short* __restrict__ agg, const unsigned short* __restrict__ hin,
    const unsigned short* __restrict__ WlT, const unsigned short* __restrict__ WrT,
    const float* __restrict__ bias, unsigned short* __restrict__ hout,
    const float* __restrict__ Wc, const float* __restrict__ bc,
    float* __restrict__ out) {
  __shared__ unsigned short As[128 * 72];
  __shared__ unsigned short Ws[128 * 72];
  __shared__ float zred[2][128];
  int t = threadIdx.x;
  int lane = t & 63;
  int wave = t >> 6;
  int wm = (wave & 1) * 64;
  int wn = (wave >> 1) * 64;
  int l15 = lane & 15;
  int quad = lane >> 4;
  int mbase = blockIdx.x * 128;

  f32x4 acc[4][4];
#pragma unroll
  for (int i = 0; i < 4; ++i)
#pragma unroll
    for (int j = 0; j < 4; ++j) acc[i][j] = (f32x4){0.f, 0.f, 0.f, 0.f};

  int r = t >> 1, seg = t & 1;
  int gn = mbase + r;

  for (int c = 0; c < 4; ++c) {
    const unsigned short* Ap = (c < 2) ? agg : hin;
    const unsigned short* Wp = (c < 2) ? WlT : WrT;
    int koff = (c & 1) * 64;
    uint4 av[4], wv[4];
    if (gn < N_NODES) {
      const uint4* ap = (const uint4*)(Ap + (size_t)gn * 128 + koff + seg * 32);
#pragma unroll
      for (int i = 0; i < 4; ++i) av[i] = ap[i];
    } else {
#pragma unroll
      for (int i = 0; i < 4; ++i) av[i] = make_uint4(0, 0, 0, 0);
    }
    const uint4* wp = (const uint4*)(Wp + (size_t)r * 128 + koff + seg * 32);
#pragma unroll
    for (int i = 0; i < 4; ++i) wv[i] = wp[i];
    __syncthreads();
#pragma unroll
    for (int i = 0; i < 4; ++i) {
      *(uint4*)&As[r * 72 + seg * 32 + i * 8] = av[i];
      *(uint4*)&Ws[r * 72 + seg * 32 + i * 8] = wv[i];
    }
    __syncthreads();
#pragma unroll
    for (int ks = 0; ks < 2; ++ks) {
      int kb = ks * 32 + quad * 8;
      bf16x8 af[4], bfr[4];
#pragma unroll
      for (int im = 0; im < 4; ++im)
        af[im] = *(const bf16x8*)&As[(wm + im * 16 + l15) * 72 + kb];
#pragma unroll
      for (int jn = 0; jn < 4; ++jn)
        bfr[jn] = *(const bf16x8*)&Ws[(wn + jn * 16 + l15) * 72 + kb];
#pragma unroll
      for (int im = 0; im < 4; ++im)
#pragma unroll
        for (int jn = 0; jn < 4; ++jn)
          acc[im][jn] = __builtin_amdgcn_mfma_f32_16x16x32_bf16(
              af[im], bfr[jn], acc[im][jn], 0, 0, 0);
    }
  }

  if (!CLS) {
    float bv[4];
#pragma unroll
    for (int jn = 0; jn < 4; ++jn) bv[jn] = bias[wn + jn * 16 + l15];
#pragma unroll
    for (int im = 0; im < 4; ++im) {
#pragma unroll
      for (int rr = 0; rr < 4; ++rr) {
        int node = mbase + wm + im * 16 + quad * 4 + rr;
        if (node < N_NODES) {
#pragma unroll
          for (int jn = 0; jn < 4; ++jn) {
            int f = wn + jn * 16 + l15;
            float zv = fmaxf(acc[im][jn][rr] + bv[jn], 0.f);
            hout[(size_t)node * 128 + f] = f2bf(zv);
          }
        }
      }
    }
  } else {
    float bv[4], wcv[4];
#pragma unroll
    for (int jn = 0; jn < 4; ++jn) {
      bv[jn] = bias[wn + jn * 16 + l15];
      wcv[jn] = Wc[wn + jn * 16 + l15];
    }
#pragma unroll
    for (int im = 0; im < 4; ++im) {
#pragma unroll
      for (int rr = 0; rr < 4; ++rr) {
        float p = 0.f;
#pragma unroll
        for (int jn = 0; jn < 4; ++jn)
          p += fmaxf(acc[im][jn][rr] + bv[jn], 0.f) * wcv[jn];
        p += __shfl_xor(p, 1);
        p += __shfl_xor(p, 2);
        p += __shfl_xor(p, 4);
        p += __shfl_xor(p, 8);
        if (l15 == 0) zred[wave >> 1][wm + im * 16 + quad * 4 + rr] = p;
      }
    }
    __syncthreads();
    if (t < 128) {
      int node = mbase + t;
      if (node < N_NODES)
        out[node] = 1.f / (1.f + expf(-(zred[0][t] + zred[1][t] + bc[0])));
    }
  }
}

// ---------------------------------------------------------------------------
extern "C" void kernel_launch(void* const* d_in, const int* in_sizes, int n_in,
                              void* d_out, int out_size, void* d_ws, size_t ws_size,
                              hipStream_t stream) {
  const float* x     = (const float*)d_in[0];
  const int*   eidx  = (const int*)d_in[1];
  const int*   uid   = (const int*)d_in[2];
  const int*   lid   = (const int*)d_in[3];
  const float* timef = (const float*)d_in[4];
  const float* utab  = (const float*)d_in[5];
  const float* ltab  = (const float*)d_in[6];
  const float* Wt    = (const float*)d_in[7];
  const float* bt    = (const float*)d_in[8];
  const float* W1l   = (const float*)d_in[9];
  const float* b1    = (const float*)d_in[10];
  const float* W1r   = (const float*)d_in[11];
  const float* W2l   = (const float*)d_in[12];
  const float* b2    = (const float*)d_in[13];
  const float* W2r   = (const float*)d_in[14];
  const float* Wc    = (const float*)d_in[15];
  const float* bc    = (const float*)d_in[16];
  float* out = (float*)d_out;

  const int E = in_sizes[1] / 2;
  const int* src = eidx;
  const int* dst = eidx + E;

  char* ws = (char*)d_ws;
  size_t off = 0;
  auto alloc = [&](size_t bytes) -> void* {
    void* p = ws + off;
    off += (bytes + 255) & ~(size_t)255;
    return p;
  };
  const size_t HBYTES = (size_t)N_NODES * 128 * sizeof(unsigned short);  // 25.6MB
  unsigned short* h0  = (unsigned short*)alloc(HBYTES);
  unsigned short* h1  = (unsigned short*)alloc(HBYTES);
  unsigned short* agg = (unsigned short*)alloc(HBYTES);  // aliased as bdata in build
  unsigned short* WT  = (unsigned short*)alloc(4 * 16384 * sizeof(unsigned short));
  int* row_ptr = (int*)alloc((size_t)(N_NODES + 1) * 4);
  int* col     = (int*)alloc((size_t)E * 4);
  int* bcnt    = (int*)alloc((size_t)NB * 16 * 4);
  int* bbase   = (int*)alloc((size_t)NB * 4);
  unsigned* bdata = (unsigned*)agg;  // 12.8MB < 25.6MB, dead after build
  (void)ws_size; (void)n_in; (void)out_size;

  // ---- embed + weight prep + bucketed CSR build ----
  hipMemsetAsync(bcnt, 0, (size_t)NB * 16 * 4, stream);
  k_embed<<<(N_NODES + 1) / 2, 256, 0, stream>>>(x, uid, lid, timef, utab, ltab, Wt, bt, h0);
  k_wprep<<<256, 256, 0, stream>>>(W1l, W1r, W2l, W2r, WT);
  k_bucket<<<(E + BTILE - 1) / BTILE, 512, 0, stream>>>(src, dst, bcnt, bdata, E);
  k_bscan<<<1, 1024, 0, stream>>>(bcnt, bbase, row_ptr);
  k_bfill<<<NB, 256, 0, stream>>>(bcnt, bbase, bdata, row_ptr, col);

  // ---- layer 1 ----
  k_agg<<<(N_NODES + 15) / 16, 256, 0, stream>>>(h0, row_ptr, col, agg);
  k_gemm<false><<<(N_NODES + 127) / 128, 256, 0, stream>>>(
      agg, h0, WT, WT + 16384, b1, h1, nullptr, nullptr, nullptr);

  // ---- layer 2 + fused classifier ----
  k_agg<<<(N_NODES + 15) / 16, 256, 0, stream>>>(h1, row_ptr, col, agg);
  k_gemm<true><<<(N_NODES + 127) / 128, 256, 0, stream>>>(
      agg, h1, WT + 32768, WT + 49152, b2, nullptr, Wc, bc, out);
}